// Round 3
// baseline (181.583 us; speedup 1.0000x reference)
//
#include <hip/hip_runtime.h>

#define NB 64
#define NN 256
#define IND 7
#define HIDD 64
#define OUTD 32
#define EPG 8192
#define ETOT 524288
#define CAPQ 2600     // CSR capacity per 64-dst quarter (mean 2112, ~12 sigma)
#define SRCPAD 2624   // CAPQ rounded to 16

typedef _Float16 f16;
typedef f16 f16x2 __attribute__((ext_vector_type(2)));
typedef f16 f16x4 __attribute__((ext_vector_type(4)));
typedef f16 f16x8 __attribute__((ext_vector_type(8)));
typedef float f32x4 __attribute__((ext_vector_type(4)));

// ---------------- block reductions for 16-wave blocks ----------------
__device__ __forceinline__ float bsum16(float v, float* rb){
#pragma unroll
  for (int o = 32; o > 0; o >>= 1) v += __shfl_xor(v, o, 64);
  __syncthreads();
  if ((threadIdx.x & 63) == 0) rb[threadIdx.x >> 6] = v;
  __syncthreads();
  float s = 0.f;
#pragma unroll
  for (int i = 0; i < 16; i++) s += rb[i];
  return s;
}

__device__ __forceinline__ f16x2 lrelu2(f16x2 s){
  const f16x2 k = {(f16)0.2f, (f16)0.2f};
  return __builtin_elementwise_max(s, s * k);
}

// ---------------- GAT layer 1 + CSR build + lin2 (fused) -------------------
// grid 512, XCD-swizzled: gs = bid&127, quarter = bid>>7. 8 thr/dst.
// xl/xr transforms use wave-uniform dim slices -> W via scalar loads (s_load),
// broadcast FMA (identical f32 fmaf chain order -> bit-identical results).
// Epilogue: lin2 (layer-2 input transforms) via MFMA on the block's 64 h rows
// (exact instruction order of the old gat2 stage -> bit-identical), storing
// xl2/xr2 so gat2 needs no weight loads at all.
__global__ __launch_bounds__(512, 4) void gat1(
    const float* __restrict__ x1, const float* __restrict__ x2,
    const int* __restrict__ e1, const int* __restrict__ e2,
    const float* __restrict__ Wl, const float* __restrict__ Wr,
    const float* __restrict__ bl, const float* __restrict__ br,
    const float* __restrict__ att, const float* __restrict__ bias,
    const float* __restrict__ Wl2, const float* __restrict__ Wr2,
    const float* __restrict__ bl2, const float* __restrict__ br2,
    f16* __restrict__ xl2, f16* __restrict__ xr2,
    int* __restrict__ meta, unsigned char* __restrict__ srcs)
{
  __shared__ __align__(16) f16 xl_s[256 * 72];   // rows padded to 144B
  __shared__ __align__(16) f16 xr1_s[64 * 72];
  __shared__ __align__(16) f16 att_s[64];
  __shared__ float sc_s[CAPQ + 8];               // +8: chunked-read overrun pad
  __shared__ unsigned int src_su[SRCPAD / 4];
  __shared__ int deg_s[64], start_s[64], cnt_s[64];
  __shared__ unsigned char perm[64];
  unsigned char* src_s = (unsigned char*)src_su;

  const int bid = blockIdx.x;
  const int gs = bid & 127, lo = (bid >> 7) * 64;
  const int side = gs >> 6, g = gs & 63;
  const float* x = side ? x2 : x1;
  const int* eb = side ? e2 : e1;
  const int* es = eb + g * EPG;
  const int* ed = eb + ETOT + g * EPG;
  const int t = threadIdx.x;
  const int wv = t >> 6, lane64 = t & 63;

  if (t < 64){ deg_s[t] = 0; att_s[t] = (f16)att[t]; }

  // ---- single global edge read -> registers (packed dst<<8|src)
  unsigned short epk[17];
  int nE = 0;
#pragma unroll
  for (int i = 0; i < 17; i++){
    int e = t + i * 512;
    if (e < EPG + 256){
      int sl, dl;
      if (e < EPG){ sl = es[e] & 255; dl = ed[e] & 255; }
      else { sl = dl = e - EPG; }
      epk[i] = (unsigned short)((dl << 8) | sl);
      nE = i + 1;
    }
  }

  // ---- xl = x@Wl + bl: wave wv -> nodes (wv&3)*64+lane, dims (wv>>2)*32..+32
  // W/b indices wave-uniform -> scalar loads; per-output k-ascending fmaf
  // chain identical to previous version -> bit-identical f32 results.
  {
    const int ng = wv & 3, dh = wv >> 2;
    const int node = ng * 64 + lane64;
    float xv[IND];
    const float* xr_ = x + (g * 256 + node) * IND;
#pragma unroll
    for (int k = 0; k < IND; k++) xv[k] = xr_[k];
    float a[32];
#pragma unroll
    for (int d = 0; d < 32; d++) a[d] = bl[dh * 32 + d];
#pragma unroll
    for (int k = 0; k < IND; k++){
      float xk = xv[k];
#pragma unroll
      for (int d = 0; d < 32; d++)
        a[d] = fmaf(xk, Wl[k * HIDD + dh * 32 + d], a[d]);
    }
#pragma unroll
    for (int c = 0; c < 4; c++){
      f16x8 o;
#pragma unroll
      for (int j = 0; j < 8; j++) o[j] = (f16)a[c * 8 + j];
      *(f16x8*)&xl_s[node * 72 + dh * 32 + c * 8] = o;
    }
  }
  // ---- xr = x@Wr + br for the 64 dsts: wave wv -> dims wv*8..+8, node=lane
  {
    const int d0 = wv * 8;
    const int node = lo + lane64;
    float xv[IND];
    const float* xq = x + (g * 256 + node) * IND;
#pragma unroll
    for (int k = 0; k < IND; k++) xv[k] = xq[k];
    float a[8];
#pragma unroll
    for (int d = 0; d < 8; d++) a[d] = br[d0 + d];
#pragma unroll
    for (int k = 0; k < IND; k++){
      float xk = xv[k];
#pragma unroll
      for (int d = 0; d < 8; d++)
        a[d] = fmaf(xk, Wr[k * HIDD + d0 + d], a[d]);
    }
    f16x8 o;
#pragma unroll
    for (int j = 0; j < 8; j++) o[j] = (f16)a[j];
    *(f16x8*)&xr1_s[lane64 * 72 + d0] = o;
  }
  __syncthreads();   // deg zero + xl_s + xr1_s + att_s visible

  // ---- CSR count pass (from regs)
#pragma unroll
  for (int i = 0; i < 17; i++) if (i < nE){
    int r = (epk[i] >> 8) - lo;
    if ((unsigned)r < 64u) atomicAdd(&deg_s[r], 1);
  }
  __syncthreads();
  // ---- scan + meta + degree-sort permutation
  if (t < 64){
    int v = deg_s[t], s = v;
#pragma unroll
    for (int off = 1; off < 64; off <<= 1){
      int u = __shfl_up(s, off, 64);
      if (t >= off) s += u;
    }
    start_s[t] = s - v;
    cnt_s[t] = s - v;
    meta[bid * 128 + t] = s - v;
    meta[bid * 128 + 64 + t] = v;
    int r = 0;
#pragma unroll 8
    for (int j = 0; j < 64; j++){
      int dj = deg_s[j];
      r += (dj < v) || (dj == v && j < t);
    }
    perm[r] = (unsigned char)t;
  }
  __syncthreads();
  // ---- fill pass (from regs)
#pragma unroll
  for (int i = 0; i < 17; i++) if (i < nE){
    int dl = epk[i] >> 8, r = dl - lo;
    if ((unsigned)r < 64u){
      int p = atomicAdd(&cnt_s[r], 1);
      if (p < CAPQ) src_s[p] = (unsigned char)(epk[i] & 255);
    }
  }
  __syncthreads();
  // ---- dump CSR srcs to global for gat2 (coalesced u32)
  {
    int ttl = start_s[63] + deg_s[63];
    if (ttl > CAPQ) ttl = CAPQ;
    unsigned int* gsrc = (unsigned int*)(srcs + (size_t)bid * SRCPAD);
    int nw = (ttl + 3) >> 2;
    for (int i = t; i < nw; i += 512) gsrc[i] = src_su[i];
  }

  // ---- 8 threads/dst (degree-sorted): xr + att fragments from LDS
  const int pairi = perm[t >> 3], sub = t & 7, ln = lo + pairi;
  f16x8 xr8[8], at8[8];
#pragma unroll
  for (int q = 0; q < 8; q++){
    xr8[q] = *(const f16x8*)&xr1_s[pairi * 72 + q * 8];
    at8[q] = *(const f16x8*)&att_s[q * 8];
  }

  // ---- scores + exp fused: edge-split (each thread every-8th edge, 64 dims)
  const int s0 = start_s[pairi];
  int sE = s0 + deg_s[pairi];
  if (sE > CAPQ) sE = CAPQ;
  float ssum = 0.f;
  for (int idx = s0 + sub; idx < sE; idx += 8){
    int sl = src_s[idx];
    const f16x8* rp = (const f16x8*)&xl_s[(unsigned)sl * 72];
    float accs[4] = {0.f, 0.f, 0.f, 0.f};
#pragma unroll
    for (int blk = 0; blk < 8; blk++){
      f16x8 rv = rp[blk];
      f16x8 xb = xr8[blk], ab = at8[blk];
#pragma unroll
      for (int u = 0; u < 4; u++){
        f16x2 v = {rv[2 * u], rv[2 * u + 1]};
        f16x2 xx = {xb[2 * u], xb[2 * u + 1]};
        f16x2 aa = {ab[2 * u], ab[2 * u + 1]};
        v = v + xx;
        accs[u] = __builtin_amdgcn_fdot2(lrelu2(v), aa, accs[u], false);
      }
    }
    float w = __expf((accs[0] + accs[1]) + (accs[2] + accs[3]));
    sc_s[idx] = w;
    ssum += w;
  }
  ssum += __shfl_xor(ssum, 1, 64);
  ssum += __shfl_xor(ssum, 2, 64);
  ssum += __shfl_xor(ssum, 4, 64);
  float inv = 1.f / ssum;
  // ---- aggregate alpha * xl[src], dim-split 8 ways, 4-deep pipelined.
  float acc[8];
#pragma unroll
  for (int c = 0; c < 8; c++) acc[c] = 0.f;
  for (int base = s0; base < sE; base += 4){
    f16x8 rows[4]; float wv_[4];
#pragma unroll
    for (int k = 0; k < 4; k++){
      int sl = src_s[base + k];
      rows[k] = *(const f16x8*)&xl_s[(unsigned)sl * 72 + sub * 8];
      wv_[k] = sc_s[base + k];
    }
#pragma unroll
    for (int k = 0; k < 4; k++){
      float w = (base + k < sE) ? wv_[k] : 0.f;
#pragma unroll
      for (int c = 0; c < 8; c++) acc[c] = fmaf(w, (float)rows[k][c], acc[c]);
    }
  }
  f16x8 o;
#pragma unroll
  for (int c = 0; c < 8; c++)
    o[c] = (f16)fmaxf(acc[c] * inv + bias[sub * 8 + c], 0.f);

  // ---- lin2 epilogue: h rows -> xl_s rows 0..63 (xl_s dead), then MFMA
  __syncthreads();                        // all xl_s readers done
  *(f16x8*)&xl_s[pairi * 72 + sub * 8] = o;
  __syncthreads();
  if (wv < 4){
    const int m = lane64 & 15, quad = lane64 >> 4;
    const int row = wv * 16 + m;
    f16x8 a0 = *(const f16x8*)&xl_s[row * 72 + quad * 8];
    f16x8 a1 = *(const f16x8*)&xl_s[row * 72 + 32 + quad * 8];
#pragma unroll
    for (int mat = 0; mat < 2; mat++){
      const float* W = mat ? Wr2 : Wl2;
      const float* bb = mat ? br2 : bl2;
      f16* dst = mat ? xr2 : xl2;
#pragma unroll
      for (int H = 0; H < 2; H++){
        const int n = H * 16 + m;
        f16x8 b0, b1;
#pragma unroll
        for (int j = 0; j < 8; j++){
          b0[j] = (f16)W[(quad * 8 + j) * 32 + n];
          b1[j] = (f16)W[(32 + quad * 8 + j) * 32 + n];
        }
        const float bv = bb[n];
        f32x4 accm = {0.f, 0.f, 0.f, 0.f};
        accm = __builtin_amdgcn_mfma_f32_16x16x32_f16(a0, b0, accm, 0, 0, 0);
        accm = __builtin_amdgcn_mfma_f32_16x16x32_f16(a1, b1, accm, 0, 0, 0);
#pragma unroll
        for (int r = 0; r < 4; r++)
          dst[(size_t)(gs * 256 + lo + wv * 16 + quad * 4 + r) * 32 + n]
              = (f16)(accm[r] + bv);
      }
    }
  }
}

// ---------------- GAT layer 2 (no weights: consumes xl2/xr2) ---------------
// Same grid/swizzle as gat1; CSR slot = blockIdx.x (matches gat1's store).
__global__ __launch_bounds__(512, 4) void gat2(
    const int* __restrict__ meta, const unsigned char* __restrict__ srcs,
    const f16* __restrict__ xl2, const f16* __restrict__ xr2,
    const float* __restrict__ att, const float* __restrict__ bias,
    f16* __restrict__ hout)
{
  __shared__ __align__(16) f16 xl_s[256 * 40];   // rows padded to 80B
  __shared__ __align__(16) f16 xr_s[64 * 40];
  __shared__ float sc_s[CAPQ + 8];               // +8: chunked-read overrun pad
  __shared__ unsigned int src_su[SRCPAD / 4];
  __shared__ int start_s[64], deg_s[64];
  __shared__ unsigned char perm[64];
  unsigned char* src_s = (unsigned char*)src_su;

  const int bid = blockIdx.x;                    // same mapping as gat1
  const int gs = bid & 127, lo = (bid >> 7) * 64;
  const int t = threadIdx.x;

  // ---- CSR load (global -> LDS)
  if (t < 64){
    start_s[t] = meta[bid * 128 + t];
    deg_s[t] = meta[bid * 128 + 64 + t];
  }
  {
    int ttl = meta[bid * 128 + 63] + meta[bid * 128 + 64 + 63];
    if (ttl > CAPQ) ttl = CAPQ;
    const unsigned int* gsrc = (const unsigned int*)(srcs + (size_t)bid * SRCPAD);
    int nw = (ttl + 3) >> 2;
    for (int i = t; i < nw; i += 512) src_su[i] = gsrc[i];
  }

  // ---- stage xl2 (all 256 srcs) and xr2 (own 64 dsts): coalesced copies
  {
    const int row = t >> 1, half = t & 1;
    const f16* s_ = xl2 + (size_t)(gs * 256 + row) * 32 + half * 16;
    *(f16x8*)&xl_s[row * 40 + half * 16] = *(const f16x8*)s_;
    *(f16x8*)&xl_s[row * 40 + half * 16 + 8] = *(const f16x8*)(s_ + 8);
    if (t < 128){
      const f16* s2_ = xr2 + (size_t)(gs * 256 + lo + row) * 32 + half * 16;
      *(f16x8*)&xr_s[row * 40 + half * 16] = *(const f16x8*)s2_;
      *(f16x8*)&xr_s[row * 40 + half * 16 + 8] = *(const f16x8*)(s2_ + 8);
    }
  }
  __syncthreads();
  // ---- degree-sort permutation
  if (t < 64){
    int v = deg_s[t], r = 0;
#pragma unroll 8
    for (int j = 0; j < 64; j++){
      int dj = deg_s[j];
      r += (dj < v) || (dj == v && j < t);
    }
    perm[r] = (unsigned char)t;
  }
  __syncthreads();

  // ---- 8 threads/dst (sorted): full 32-dim xr + att in regs
  const int pairi = perm[t >> 3], sub = t & 7, ln = lo + pairi;
  f16x2 xrh[16], atth[16];
  {
    const f16x8* xrp = (const f16x8*)&xr_s[pairi * 40];
#pragma unroll
    for (int q = 0; q < 4; q++){
      f16x8 v = xrp[q];
#pragma unroll
      for (int u = 0; u < 4; u++){
        xrh[q * 4 + u][0] = v[2 * u];
        xrh[q * 4 + u][1] = v[2 * u + 1];
      }
    }
#pragma unroll
    for (int i = 0; i < 16; i++){
      atth[i][0] = (f16)att[2 * i];
      atth[i][1] = (f16)att[2 * i + 1];
    }
  }

  // ---- scores + exp fused: edge-split
  const int s0 = start_s[pairi];
  int sE = s0 + deg_s[pairi];
  if (sE > CAPQ) sE = CAPQ;
  float ssum = 0.f;
  for (int idx = s0 + sub; idx < sE; idx += 8){
    int sl = src_s[idx];
    const f16x8* rp = (const f16x8*)&xl_s[(unsigned)sl * 40];
    float accs[4] = {0.f, 0.f, 0.f, 0.f};
#pragma unroll
    for (int blk = 0; blk < 4; blk++){
      f16x8 rv = rp[blk];
#pragma unroll
      for (int u = 0; u < 4; u++){
        f16x2 v = {rv[2 * u], rv[2 * u + 1]};
        v = v + xrh[blk * 4 + u];
        accs[u] = __builtin_amdgcn_fdot2(lrelu2(v), atth[blk * 4 + u], accs[u], false);
      }
    }
    float w = __expf((accs[0] + accs[1]) + (accs[2] + accs[3]));
    sc_s[idx] = w;
    ssum += w;
  }
  ssum += __shfl_xor(ssum, 1, 64);
  ssum += __shfl_xor(ssum, 2, 64);
  ssum += __shfl_xor(ssum, 4, 64);
  float inv = 1.f / ssum;

  // ---- aggregate, dim-split 4 ways per thread-octet, 8-deep pipelined
  float acc[4];
#pragma unroll
  for (int c = 0; c < 4; c++) acc[c] = 0.f;
  for (int base = s0; base < sE; base += 8){
    f16x4 rows[8]; float wv[8];
#pragma unroll
    for (int k = 0; k < 8; k++){
      int sl = src_s[base + k];
      rows[k] = *(const f16x4*)&xl_s[(unsigned)sl * 40 + sub * 4];
      wv[k] = sc_s[base + k];
    }
#pragma unroll
    for (int k = 0; k < 8; k++){
      float w = (base + k < sE) ? wv[k] : 0.f;
#pragma unroll
      for (int c = 0; c < 4; c++) acc[c] = fmaf(w, (float)rows[k][c], acc[c]);
    }
  }
  f16x4 o;
#pragma unroll
  for (int c = 0; c < 4; c++)
    o[c] = (f16)(acc[c] * inv + bias[sub * 4 + c]);
  *(f16x4*)(hout + (size_t)(gs * 256 + ln) * 32 + sub * 4) = o;
}

// ---------------- sinkout: fused sim + stats + histogram Sinkhorn + output --
// grid 256 XCD-swizzled (b = bid&63, q = bid>>6), 1024 thr (16 waves).
__global__ __launch_bounds__(1024) void sinkout(
    const f16* __restrict__ H,
    const float* __restrict__ gamma, const float* __restrict__ beta,
    float* __restrict__ out)
{
  __shared__ float rb[16];
  __shared__ __align__(16) float rb4s[64];   // 16 waves x (sum,sumsq,min,max)
  __shared__ unsigned int hist[8192];
  const int b = blockIdx.x & 63, q = blockIdx.x >> 6, t = threadIdx.x;
  const int w = t >> 6, lane = t & 63;
  const int m = lane & 15, quad = lane >> 4;

  const f16* h1 = H + (size_t)b * 256 * 32;
  const f16* h2 = H + (size_t)(64 + b) * 256 * 32;

  f16x8 av = *(const f16x8*)(h1 + (size_t)(w * 16 + m) * 32 + quad * 8);
  f32x4 c[16];
#pragma unroll
  for (int j = 0; j < 16; j++){
    f16x8 bv = *(const f16x8*)(h2 + (size_t)(j * 16 + m) * 32 + quad * 8);
    f32x4 z = {0.f, 0.f, 0.f, 0.f};
    c[j] = __builtin_amdgcn_mfma_f32_16x16x32_f16(av, bv, z, 0, 0, 0);
  }

  // ---- stats over reg-resident sim: packed single-barrier reduction
  float sm = 0.f, s2 = 0.f, mn = 3.0e38f, mx = -3.0e38f;
#pragma unroll
  for (int j = 0; j < 16; j++)
#pragma unroll
    for (int r = 0; r < 4; r++){
      float s = c[j][r];
      sm += s; s2 = fmaf(s, s, s2);
      mn = fminf(mn, s); mx = fmaxf(mx, s);
    }
#pragma unroll
  for (int o = 32; o > 0; o >>= 1){
    sm += __shfl_xor(sm, o, 64);
    s2 += __shfl_xor(s2, o, 64);
    mn = fminf(mn, __shfl_xor(mn, o, 64));
    mx = fmaxf(mx, __shfl_xor(mx, o, 64));
  }
  if (lane == 0){
    rb4s[w * 4 + 0] = sm; rb4s[w * 4 + 1] = s2;
    rb4s[w * 4 + 2] = mn; rb4s[w * 4 + 3] = mx;
  }
  // hist zero-init shares the same barrier
  for (int i = t; i < 8192; i += 1024) hist[i] = 0u;
  __syncthreads();
  sm = 0.f; s2 = 0.f; mn = 3.0e38f; mx = -3.0e38f;
#pragma unroll
  for (int i = 0; i < 16; i++){
    sm += rb4s[i * 4 + 0];
    s2 += rb4s[i * 4 + 1];
    mn = fminf(mn, rb4s[i * 4 + 2]);
    mx = fmaxf(mx, rb4s[i * 4 + 3]);
  }

  const float mu = sm * (1.f / 65536.f);
  const float var = s2 * (1.f / 65536.f) - mu * mu;
  const float a = gamma[0] * rsqrtf(var + 1e-5f);
  const float cc = beta[0] - a * mu;
  float mnn = a * mn + cc, mxn = a * mx + cc;
  if (a < 0.f){ float tmp = mnn; mnn = mxn; mxn = tmp; }
  const float al = 2.f * a;
  const float be = 2.f * cc - mnn - mxn;
  const float R = fmaxf(mxn - mnn, 1e-12f);       // z in [-R, R]
  const float binscale = 4096.f / R;

  // ---- histogram from f32 sim (hist already zeroed before the barrier)
#pragma unroll
  for (int j = 0; j < 16; j++)
#pragma unroll
    for (int r = 0; r < 4; r++){
      float z = fmaf(al, c[j][r], be);
      int bi = (int)fmaf(z, binscale, 4096.f);
      bi = min(max(bi, 0), 8191);
      atomicAdd(&hist[bi], 1u);
    }
  __syncthreads();

  // ---- 5 S_p reductions over bins (8 bins/thread)
  const float wbin = R * (1.f / 4096.f);
  float ebs[8], cnts[8];
#pragma unroll
  for (int j = 0; j < 8; j++){
    float zc = fmaf((float)(t * 8 + j) + 0.5f, wbin, -R);
    ebs[j] = __expf(-zc);
    cnts[j] = (float)hist[t * 8 + j];
  }

  float D = 0.f, S = 256.f, eD = 1.f;
  for (int p = 0; p < 5; p++){
    float loc = 0.f;
#pragma unroll
    for (int j = 0; j < 8; j++)
      loc += cnts[j] / (1.f + ebs[j] * eD);
    S = bsum16(loc, rb);
    if (p < 4){
      D += -5.5412635f /* log(256/65280) */ + __logf(65536.f - S) - __logf(S);
      eD = __expf(-D);
    }
  }

  // ---- write my 64-row quarter: waves 4q..4q+3 own rows [64q, 64q+64)
  const float beD = be + D;
  const float scale = 256.f / S;
  if ((w >> 2) == q){
    float* ob = out + (size_t)b * 65536;
#pragma unroll
    for (int j = 0; j < 16; j++){
#pragma unroll
      for (int r = 0; r < 4; r++){
        float zz = fmaf(al, c[j][r], beD);
        float v = fminf(scale / (1.f + __expf(-zz)), 1.f);
        ob[(w * 16 + quad * 4 + r) * 256 + j * 16 + m] = v;
      }
    }
  }
}

extern "C" void kernel_launch(void* const* d_in, const int* in_sizes, int n_in,
                              void* d_out, int out_size, void* d_ws, size_t ws_size,
                              hipStream_t stream)
{
  const float* x1   = (const float*)d_in[0];
  const float* x2   = (const float*)d_in[1];
  const int*   e1   = (const int*)d_in[2];
  const int*   e2   = (const int*)d_in[3];
  const float* Wl1  = (const float*)d_in[4];
  const float* Wr1  = (const float*)d_in[5];
  const float* bl1  = (const float*)d_in[6];
  const float* br1  = (const float*)d_in[7];
  const float* att1 = (const float*)d_in[8];
  const float* bias1= (const float*)d_in[9];
  const float* Wl2  = (const float*)d_in[10];
  const float* Wr2  = (const float*)d_in[11];
  const float* bl2  = (const float*)d_in[12];
  const float* br2  = (const float*)d_in[13];
  const float* att2 = (const float*)d_in[14];
  const float* bias2= (const float*)d_in[15];
  const float* gamma= (const float*)d_in[16];
  const float* beta = (const float*)d_in[17];

  // ws (~7.9 MB): hfin [0,2M); xl2 [2M,4M); xr2 [4M,6M); meta [6M,+256K);
  // srcs [+256K,+1.6M).
  char* ws = (char*)d_ws;
  f16* hfin = (f16*)ws;
  f16* xl2 = (f16*)(ws + (size_t)2 * 1024 * 1024);
  f16* xr2 = (f16*)(ws + (size_t)4 * 1024 * 1024);
  int* meta = (int*)(ws + (size_t)6 * 1024 * 1024);
  unsigned char* srcs = (unsigned char*)(ws + (size_t)6 * 1024 * 1024 + 512 * 128 * 4);
  float* out = (float*)d_out;

  gat1<<<512, 512, 0, stream>>>(x1, x2, e1, e2, Wl1, Wr1, bl1, br1, att1, bias1,
                                Wl2, Wr2, bl2, br2, xl2, xr2, meta, srcs);
  gat2<<<512, 512, 0, stream>>>(meta, srcs, xl2, xr2, att2, bias2, hfin);
  sinkout<<<256, 1024, 0, stream>>>(hfin, gamma, beta, out);
}

// Round 5
// 175.936 us; speedup vs baseline: 1.0321x; 1.0321x over previous
//
#include <hip/hip_runtime.h>

#define NB 64
#define NN 256
#define IND 7
#define HIDD 64
#define OUTD 32
#define EPG 8192
#define ETOT 524288
#define CAPQ 2600     // CSR capacity per 64-dst quarter (mean 2112, ~12 sigma)
#define SRCPAD 2624   // CAPQ rounded to 16

typedef _Float16 f16;
typedef f16 f16x2 __attribute__((ext_vector_type(2)));
typedef f16 f16x4 __attribute__((ext_vector_type(4)));
typedef f16 f16x8 __attribute__((ext_vector_type(8)));
typedef float f32x4 __attribute__((ext_vector_type(4)));

// ---------------- block reductions for 16-wave blocks ----------------
__device__ __forceinline__ float bsum16(float v, float* rb){
#pragma unroll
  for (int o = 32; o > 0; o >>= 1) v += __shfl_xor(v, o, 64);
  __syncthreads();
  if ((threadIdx.x & 63) == 0) rb[threadIdx.x >> 6] = v;
  __syncthreads();
  float s = 0.f;
#pragma unroll
  for (int i = 0; i < 16; i++) s += rb[i];
  return s;
}

__device__ __forceinline__ f16x2 lrelu2(f16x2 s){
  const f16x2 k = {(f16)0.2f, (f16)0.2f};
  return __builtin_elementwise_max(s, s * k);
}

// ---------------- GAT layer 1 + CSR build + lin2 (fused) -------------------
// grid 512, XCD-swizzled: gs = bid&127, quarter = bid>>7. 8 thr/dst.
// xl/xr transforms use wave-uniform dim slices -> W via scalar loads; the
// accumulators are CHUNKED 8-wide (ch loop) to keep live VGPRs < 64 — the
// 32-wide variant spilled to scratch (R3: +40MB WRITE_SIZE, gat1 40->57us).
// Per-output fmaf chains stay k-ascending -> bit-identical results.
// Epilogue: lin2 (layer-2 input transforms) via MFMA on the block's 64 h rows
// storing xl2/xr2 so gat2 needs no weight loads at all.
__global__ __launch_bounds__(512, 4) void gat1(
    const float* __restrict__ x1, const float* __restrict__ x2,
    const int* __restrict__ e1, const int* __restrict__ e2,
    const float* __restrict__ Wl, const float* __restrict__ Wr,
    const float* __restrict__ bl, const float* __restrict__ br,
    const float* __restrict__ att, const float* __restrict__ bias,
    const float* __restrict__ Wl2, const float* __restrict__ Wr2,
    const float* __restrict__ bl2, const float* __restrict__ br2,
    f16* __restrict__ xl2, f16* __restrict__ xr2,
    int* __restrict__ meta, unsigned char* __restrict__ srcs)
{
  __shared__ __align__(16) f16 xl_s[256 * 72];   // rows padded to 144B
  __shared__ __align__(16) f16 xr1_s[64 * 72];
  __shared__ __align__(16) f16 att_s[64];
  __shared__ float sc_s[CAPQ + 8];               // +8: chunked-read overrun pad
  __shared__ unsigned int src_su[SRCPAD / 4];
  __shared__ int deg_s[64], start_s[64], cnt_s[64];
  __shared__ unsigned char perm[64];
  unsigned char* src_s = (unsigned char*)src_su;

  const int bid = blockIdx.x;
  const int gs = bid & 127, lo = (bid >> 7) * 64;
  const int side = gs >> 6, g = gs & 63;
  const float* x = side ? x2 : x1;
  const int* eb = side ? e2 : e1;
  const int* es = eb + g * EPG;
  const int* ed = eb + ETOT + g * EPG;
  const int t = threadIdx.x;
  const int wv = t >> 6, lane64 = t & 63;

  if (t < 64){ deg_s[t] = 0; att_s[t] = (f16)att[t]; }

  // ---- single global edge read -> registers (packed dst<<8|src)
  unsigned short epk[17];
  int nE = 0;
#pragma unroll
  for (int i = 0; i < 17; i++){
    int e = t + i * 512;
    if (e < EPG + 256){
      int sl, dl;
      if (e < EPG){ sl = es[e] & 255; dl = ed[e] & 255; }
      else { sl = dl = e - EPG; }
      epk[i] = (unsigned short)((dl << 8) | sl);
      nE = i + 1;
    }
  }

  // ---- xl = x@Wl + bl: wave wv -> nodes (wv&3)*64+lane, dims (wv>>2)*32..+32
  // chunked 8-wide accumulators (no spill); W/b wave-uniform -> scalar loads.
  {
    const int ng = wv & 3, dh = wv >> 2;
    const int node = ng * 64 + lane64;
    float xv[IND];
    const float* xr_ = x + (g * 256 + node) * IND;
#pragma unroll
    for (int k = 0; k < IND; k++) xv[k] = xr_[k];
#pragma unroll
    for (int ch = 0; ch < 4; ch++){
      const int d0 = dh * 32 + ch * 8;
      float a[8];
#pragma unroll
      for (int d = 0; d < 8; d++) a[d] = bl[d0 + d];
#pragma unroll
      for (int k = 0; k < IND; k++){
        float xk = xv[k];
#pragma unroll
        for (int d = 0; d < 8; d++)
          a[d] = fmaf(xk, Wl[k * HIDD + d0 + d], a[d]);
      }
      f16x8 o;
#pragma unroll
      for (int j = 0; j < 8; j++) o[j] = (f16)a[j];
      *(f16x8*)&xl_s[node * 72 + d0] = o;
    }
  }
  // ---- xr = x@Wr + br for the 64 dsts: wave wv -> dims wv*8..+8, node=lane
  {
    const int d0 = wv * 8;
    const int node = lo + lane64;
    float xv[IND];
    const float* xq = x + (g * 256 + node) * IND;
#pragma unroll
    for (int k = 0; k < IND; k++) xv[k] = xq[k];
    float a[8];
#pragma unroll
    for (int d = 0; d < 8; d++) a[d] = br[d0 + d];
#pragma unroll
    for (int k = 0; k < IND; k++){
      float xk = xv[k];
#pragma unroll
      for (int d = 0; d < 8; d++)
        a[d] = fmaf(xk, Wr[k * HIDD + d0 + d], a[d]);
    }
    f16x8 o;
#pragma unroll
    for (int j = 0; j < 8; j++) o[j] = (f16)a[j];
    *(f16x8*)&xr1_s[lane64 * 72 + d0] = o;
  }
  __syncthreads();   // deg zero + xl_s + xr1_s + att_s visible

  // ---- CSR count pass (from regs)
#pragma unroll
  for (int i = 0; i < 17; i++) if (i < nE){
    int r = (epk[i] >> 8) - lo;
    if ((unsigned)r < 64u) atomicAdd(&deg_s[r], 1);
  }
  __syncthreads();
  // ---- scan + meta + degree-sort permutation
  if (t < 64){
    int v = deg_s[t], s = v;
#pragma unroll
    for (int off = 1; off < 64; off <<= 1){
      int u = __shfl_up(s, off, 64);
      if (t >= off) s += u;
    }
    start_s[t] = s - v;
    cnt_s[t] = s - v;
    meta[bid * 128 + t] = s - v;
    meta[bid * 128 + 64 + t] = v;
    int r = 0;
#pragma unroll 8
    for (int j = 0; j < 64; j++){
      int dj = deg_s[j];
      r += (dj < v) || (dj == v && j < t);
    }
    perm[r] = (unsigned char)t;
  }
  __syncthreads();
  // ---- fill pass (from regs)
#pragma unroll
  for (int i = 0; i < 17; i++) if (i < nE){
    int dl = epk[i] >> 8, r = dl - lo;
    if ((unsigned)r < 64u){
      int p = atomicAdd(&cnt_s[r], 1);
      if (p < CAPQ) src_s[p] = (unsigned char)(epk[i] & 255);
    }
  }
  __syncthreads();
  // ---- dump CSR srcs to global for gat2 (coalesced u32)
  {
    int ttl = start_s[63] + deg_s[63];
    if (ttl > CAPQ) ttl = CAPQ;
    unsigned int* gsrc = (unsigned int*)(srcs + (size_t)bid * SRCPAD);
    int nw = (ttl + 3) >> 2;
    for (int i = t; i < nw; i += 512) gsrc[i] = src_su[i];
  }

  // ---- 8 threads/dst (degree-sorted): xr + att fragments from LDS
  const int pairi = perm[t >> 3], sub = t & 7, ln = lo + pairi;
  f16x8 xr8[8], at8[8];
#pragma unroll
  for (int q = 0; q < 8; q++){
    xr8[q] = *(const f16x8*)&xr1_s[pairi * 72 + q * 8];
    at8[q] = *(const f16x8*)&att_s[q * 8];
  }

  // ---- scores + exp fused: edge-split (each thread every-8th edge, 64 dims)
  const int s0 = start_s[pairi];
  int sE = s0 + deg_s[pairi];
  if (sE > CAPQ) sE = CAPQ;
  float ssum = 0.f;
  for (int idx = s0 + sub; idx < sE; idx += 8){
    int sl = src_s[idx];
    const f16x8* rp = (const f16x8*)&xl_s[(unsigned)sl * 72];
    float accs[4] = {0.f, 0.f, 0.f, 0.f};
#pragma unroll
    for (int blk = 0; blk < 8; blk++){
      f16x8 rv = rp[blk];
      f16x8 xb = xr8[blk], ab = at8[blk];
#pragma unroll
      for (int u = 0; u < 4; u++){
        f16x2 v = {rv[2 * u], rv[2 * u + 1]};
        f16x2 xx = {xb[2 * u], xb[2 * u + 1]};
        f16x2 aa = {ab[2 * u], ab[2 * u + 1]};
        v = v + xx;
        accs[u] = __builtin_amdgcn_fdot2(lrelu2(v), aa, accs[u], false);
      }
    }
    float w = __expf((accs[0] + accs[1]) + (accs[2] + accs[3]));
    sc_s[idx] = w;
    ssum += w;
  }
  ssum += __shfl_xor(ssum, 1, 64);
  ssum += __shfl_xor(ssum, 2, 64);
  ssum += __shfl_xor(ssum, 4, 64);
  float inv = 1.f / ssum;
  // ---- aggregate alpha * xl[src], dim-split 8 ways, 4-deep pipelined.
  float acc[8];
#pragma unroll
  for (int c = 0; c < 8; c++) acc[c] = 0.f;
  for (int base = s0; base < sE; base += 4){
    f16x8 rows[4]; float wv_[4];
#pragma unroll
    for (int k = 0; k < 4; k++){
      int sl = src_s[base + k];
      rows[k] = *(const f16x8*)&xl_s[(unsigned)sl * 72 + sub * 8];
      wv_[k] = sc_s[base + k];
    }
#pragma unroll
    for (int k = 0; k < 4; k++){
      float w = (base + k < sE) ? wv_[k] : 0.f;
#pragma unroll
      for (int c = 0; c < 8; c++) acc[c] = fmaf(w, (float)rows[k][c], acc[c]);
    }
  }
  f16x8 o;
#pragma unroll
  for (int c = 0; c < 8; c++)
    o[c] = (f16)fmaxf(acc[c] * inv + bias[sub * 8 + c], 0.f);

  // ---- lin2 epilogue: h rows -> xl_s rows 0..63 (xl_s dead), then MFMA
  __syncthreads();                        // all xl_s readers done
  *(f16x8*)&xl_s[pairi * 72 + sub * 8] = o;
  __syncthreads();
  if (wv < 4){
    const int m = lane64 & 15, quad = lane64 >> 4;
    const int row = wv * 16 + m;
    f16x8 a0 = *(const f16x8*)&xl_s[row * 72 + quad * 8];
    f16x8 a1 = *(const f16x8*)&xl_s[row * 72 + 32 + quad * 8];
#pragma unroll
    for (int mat = 0; mat < 2; mat++){
      const float* W = mat ? Wr2 : Wl2;
      const float* bb = mat ? br2 : bl2;
      f16* dst = mat ? xr2 : xl2;
#pragma unroll
      for (int H = 0; H < 2; H++){
        const int n = H * 16 + m;
        f16x8 b0, b1;
#pragma unroll
        for (int j = 0; j < 8; j++){
          b0[j] = (f16)W[(quad * 8 + j) * 32 + n];
          b1[j] = (f16)W[(32 + quad * 8 + j) * 32 + n];
        }
        const float bv = bb[n];
        f32x4 accm = {0.f, 0.f, 0.f, 0.f};
        accm = __builtin_amdgcn_mfma_f32_16x16x32_f16(a0, b0, accm, 0, 0, 0);
        accm = __builtin_amdgcn_mfma_f32_16x16x32_f16(a1, b1, accm, 0, 0, 0);
#pragma unroll
        for (int r = 0; r < 4; r++)
          dst[(size_t)(gs * 256 + lo + wv * 16 + quad * 4 + r) * 32 + n]
              = (f16)(accm[r] + bv);
      }
    }
  }
}

// ---------------- GAT layer 2 (no weights: consumes xl2/xr2) ---------------
// Same grid/swizzle as gat1; CSR slot = blockIdx.x (matches gat1's store).
__global__ __launch_bounds__(512, 4) void gat2(
    const int* __restrict__ meta, const unsigned char* __restrict__ srcs,
    const f16* __restrict__ xl2, const f16* __restrict__ xr2,
    const float* __restrict__ att, const float* __restrict__ bias,
    f16* __restrict__ hout)
{
  __shared__ __align__(16) f16 xl_s[256 * 40];   // rows padded to 80B
  __shared__ __align__(16) f16 xr_s[64 * 40];
  __shared__ float sc_s[CAPQ + 8];               // +8: chunked-read overrun pad
  __shared__ unsigned int src_su[SRCPAD / 4];
  __shared__ int start_s[64], deg_s[64];
  __shared__ unsigned char perm[64];
  unsigned char* src_s = (unsigned char*)src_su;

  const int bid = blockIdx.x;                    // same mapping as gat1
  const int gs = bid & 127, lo = (bid >> 7) * 64;
  const int t = threadIdx.x;

  // ---- CSR load (global -> LDS)
  if (t < 64){
    start_s[t] = meta[bid * 128 + t];
    deg_s[t] = meta[bid * 128 + 64 + t];
  }
  {
    int ttl = meta[bid * 128 + 63] + meta[bid * 128 + 64 + 63];
    if (ttl > CAPQ) ttl = CAPQ;
    const unsigned int* gsrc = (const unsigned int*)(srcs + (size_t)bid * SRCPAD);
    int nw = (ttl + 3) >> 2;
    for (int i = t; i < nw; i += 512) src_su[i] = gsrc[i];
  }

  // ---- stage xl2 (all 256 srcs) and xr2 (own 64 dsts): coalesced copies
  {
    const int row = t >> 1, half = t & 1;
    const f16* s_ = xl2 + (size_t)(gs * 256 + row) * 32 + half * 16;
    *(f16x8*)&xl_s[row * 40 + half * 16] = *(const f16x8*)s_;
    *(f16x8*)&xl_s[row * 40 + half * 16 + 8] = *(const f16x8*)(s_ + 8);
    if (t < 128){
      const f16* s2_ = xr2 + (size_t)(gs * 256 + lo + row) * 32 + half * 16;
      *(f16x8*)&xr_s[row * 40 + half * 16] = *(const f16x8*)s2_;
      *(f16x8*)&xr_s[row * 40 + half * 16 + 8] = *(const f16x8*)(s2_ + 8);
    }
  }
  __syncthreads();
  // ---- degree-sort permutation
  if (t < 64){
    int v = deg_s[t], r = 0;
#pragma unroll 8
    for (int j = 0; j < 64; j++){
      int dj = deg_s[j];
      r += (dj < v) || (dj == v && j < t);
    }
    perm[r] = (unsigned char)t;
  }
  __syncthreads();

  // ---- 8 threads/dst (sorted): full 32-dim xr + att in regs
  const int pairi = perm[t >> 3], sub = t & 7, ln = lo + pairi;
  f16x2 xrh[16], atth[16];
  {
    const f16x8* xrp = (const f16x8*)&xr_s[pairi * 40];
#pragma unroll
    for (int q = 0; q < 4; q++){
      f16x8 v = xrp[q];
#pragma unroll
      for (int u = 0; u < 4; u++){
        xrh[q * 4 + u][0] = v[2 * u];
        xrh[q * 4 + u][1] = v[2 * u + 1];
      }
    }
#pragma unroll
    for (int i = 0; i < 16; i++){
      atth[i][0] = (f16)att[2 * i];
      atth[i][1] = (f16)att[2 * i + 1];
    }
  }

  // ---- scores + exp fused: edge-split
  const int s0 = start_s[pairi];
  int sE = s0 + deg_s[pairi];
  if (sE > CAPQ) sE = CAPQ;
  float ssum = 0.f;
  for (int idx = s0 + sub; idx < sE; idx += 8){
    int sl = src_s[idx];
    const f16x8* rp = (const f16x8*)&xl_s[(unsigned)sl * 40];
    float accs[4] = {0.f, 0.f, 0.f, 0.f};
#pragma unroll
    for (int blk = 0; blk < 4; blk++){
      f16x8 rv = rp[blk];
#pragma unroll
      for (int u = 0; u < 4; u++){
        f16x2 v = {rv[2 * u], rv[2 * u + 1]};
        v = v + xrh[blk * 4 + u];
        accs[u] = __builtin_amdgcn_fdot2(lrelu2(v), atth[blk * 4 + u], accs[u], false);
      }
    }
    float w = __expf((accs[0] + accs[1]) + (accs[2] + accs[3]));
    sc_s[idx] = w;
    ssum += w;
  }
  ssum += __shfl_xor(ssum, 1, 64);
  ssum += __shfl_xor(ssum, 2, 64);
  ssum += __shfl_xor(ssum, 4, 64);
  float inv = 1.f / ssum;

  // ---- aggregate, dim-split 4 ways per thread-octet, 8-deep pipelined
  float acc[4];
#pragma unroll
  for (int c = 0; c < 4; c++) acc[c] = 0.f;
  for (int base = s0; base < sE; base += 8){
    f16x4 rows[8]; float wv[8];
#pragma unroll
    for (int k = 0; k < 8; k++){
      int sl = src_s[base + k];
      rows[k] = *(const f16x4*)&xl_s[(unsigned)sl * 40 + sub * 4];
      wv[k] = sc_s[base + k];
    }
#pragma unroll
    for (int k = 0; k < 8; k++){
      float w = (base + k < sE) ? wv[k] : 0.f;
#pragma unroll
      for (int c = 0; c < 4; c++) acc[c] = fmaf(w, (float)rows[k][c], acc[c]);
    }
  }
  f16x4 o;
#pragma unroll
  for (int c = 0; c < 4; c++)
    o[c] = (f16)(acc[c] * inv + bias[sub * 4 + c]);
  *(f16x4*)(hout + (size_t)(gs * 256 + ln) * 32 + sub * 4) = o;
}

// ---------------- sinkout: fused sim + stats + histogram Sinkhorn + output --
// grid 256 XCD-swizzled (b = bid&63, q = bid>>6), 1024 thr (16 waves).
__global__ __launch_bounds__(1024) void sinkout(
    const f16* __restrict__ H,
    const float* __restrict__ gamma, const float* __restrict__ beta,
    float* __restrict__ out)
{
  __shared__ float rb[16];
  __shared__ __align__(16) float rb4s[64];   // 16 waves x (sum,sumsq,min,max)
  __shared__ unsigned int hist[8192];
  const int b = blockIdx.x & 63, q = blockIdx.x >> 6, t = threadIdx.x;
  const int w = t >> 6, lane = t & 63;
  const int m = lane & 15, quad = lane >> 4;

  const f16* h1 = H + (size_t)b * 256 * 32;
  const f16* h2 = H + (size_t)(64 + b) * 256 * 32;

  f16x8 av = *(const f16x8*)(h1 + (size_t)(w * 16 + m) * 32 + quad * 8);
  f32x4 c[16];
#pragma unroll
  for (int j = 0; j < 16; j++){
    f16x8 bv = *(const f16x8*)(h2 + (size_t)(j * 16 + m) * 32 + quad * 8);
    f32x4 z = {0.f, 0.f, 0.f, 0.f};
    c[j] = __builtin_amdgcn_mfma_f32_16x16x32_f16(av, bv, z, 0, 0, 0);
  }

  // ---- stats over reg-resident sim: packed single-barrier reduction
  float sm = 0.f, s2 = 0.f, mn = 3.0e38f, mx = -3.0e38f;
#pragma unroll
  for (int j = 0; j < 16; j++)
#pragma unroll
    for (int r = 0; r < 4; r++){
      float s = c[j][r];
      sm += s; s2 = fmaf(s, s, s2);
      mn = fminf(mn, s); mx = fmaxf(mx, s);
    }
#pragma unroll
  for (int o = 32; o > 0; o >>= 1){
    sm += __shfl_xor(sm, o, 64);
    s2 += __shfl_xor(s2, o, 64);
    mn = fminf(mn, __shfl_xor(mn, o, 64));
    mx = fmaxf(mx, __shfl_xor(mx, o, 64));
  }
  if (lane == 0){
    rb4s[w * 4 + 0] = sm; rb4s[w * 4 + 1] = s2;
    rb4s[w * 4 + 2] = mn; rb4s[w * 4 + 3] = mx;
  }
  // hist zero-init shares the same barrier
  for (int i = t; i < 8192; i += 1024) hist[i] = 0u;
  __syncthreads();
  sm = 0.f; s2 = 0.f; mn = 3.0e38f; mx = -3.0e38f;
#pragma unroll
  for (int i = 0; i < 16; i++){
    sm += rb4s[i * 4 + 0];
    s2 += rb4s[i * 4 + 1];
    mn = fminf(mn, rb4s[i * 4 + 2]);
    mx = fmaxf(mx, rb4s[i * 4 + 3]);
  }

  const float mu = sm * (1.f / 65536.f);
  const float var = s2 * (1.f / 65536.f) - mu * mu;
  const float a = gamma[0] * rsqrtf(var + 1e-5f);
  const float cc = beta[0] - a * mu;
  float mnn = a * mn + cc, mxn = a * mx + cc;
  if (a < 0.f){ float tmp = mnn; mnn = mxn; mxn = tmp; }
  const float al = 2.f * a;
  const float be = 2.f * cc - mnn - mxn;
  const float R = fmaxf(mxn - mnn, 1e-12f);       // z in [-R, R]
  const float binscale = 4096.f / R;

  // ---- histogram from f32 sim (hist already zeroed before the barrier)
#pragma unroll
  for (int j = 0; j < 16; j++)
#pragma unroll
    for (int r = 0; r < 4; r++){
      float z = fmaf(al, c[j][r], be);
      int bi = (int)fmaf(z, binscale, 4096.f);
      bi = min(max(bi, 0), 8191);
      atomicAdd(&hist[bi], 1u);
    }
  __syncthreads();

  // ---- 5 S_p reductions over bins (8 bins/thread)
  const float wbin = R * (1.f / 4096.f);
  float ebs[8], cnts[8];
#pragma unroll
  for (int j = 0; j < 8; j++){
    float zc = fmaf((float)(t * 8 + j) + 0.5f, wbin, -R);
    ebs[j] = __expf(-zc);
    cnts[j] = (float)hist[t * 8 + j];
  }

  float D = 0.f, S = 256.f, eD = 1.f;
  for (int p = 0; p < 5; p++){
    float loc = 0.f;
#pragma unroll
    for (int j = 0; j < 8; j++)
      loc += cnts[j] / (1.f + ebs[j] * eD);
    S = bsum16(loc, rb);
    if (p < 4){
      D += -5.5412635f /* log(256/65280) */ + __logf(65536.f - S) - __logf(S);
      eD = __expf(-D);
    }
  }

  // ---- write my 64-row quarter: waves 4q..4q+3 own rows [64q, 64q+64)
  const float beD = be + D;
  const float scale = 256.f / S;
  if ((w >> 2) == q){
    float* ob = out + (size_t)b * 65536;
#pragma unroll
    for (int j = 0; j < 16; j++){
#pragma unroll
      for (int r = 0; r < 4; r++){
        float zz = fmaf(al, c[j][r], beD);
        float v = fminf(scale / (1.f + __expf(-zz)), 1.f);
        ob[(w * 16 + quad * 4 + r) * 256 + j * 16 + m] = v;
      }
    }
  }
}

extern "C" void kernel_launch(void* const* d_in, const int* in_sizes, int n_in,
                              void* d_out, int out_size, void* d_ws, size_t ws_size,
                              hipStream_t stream)
{
  const float* x1   = (const float*)d_in[0];
  const float* x2   = (const float*)d_in[1];
  const int*   e1   = (const int*)d_in[2];
  const int*   e2   = (const int*)d_in[3];
  const float* Wl1  = (const float*)d_in[4];
  const float* Wr1  = (const float*)d_in[5];
  const float* bl1  = (const float*)d_in[6];
  const float* br1  = (const float*)d_in[7];
  const float* att1 = (const float*)d_in[8];
  const float* bias1= (const float*)d_in[9];
  const float* Wl2  = (const float*)d_in[10];
  const float* Wr2  = (const float*)d_in[11];
  const float* bl2  = (const float*)d_in[12];
  const float* br2  = (const float*)d_in[13];
  const float* att2 = (const float*)d_in[14];
  const float* bias2= (const float*)d_in[15];
  const float* gamma= (const float*)d_in[16];
  const float* beta = (const float*)d_in[17];

  // ws (~7.9 MB): hfin [0,2M); xl2 [2M,4M); xr2 [4M,6M); meta [6M,+256K);
  // srcs [+256K,+1.6M).
  char* ws = (char*)d_ws;
  f16* hfin = (f16*)ws;
  f16* xl2 = (f16*)(ws + (size_t)2 * 1024 * 1024);
  f16* xr2 = (f16*)(ws + (size_t)4 * 1024 * 1024);
  int* meta = (int*)(ws + (size_t)6 * 1024 * 1024);
  unsigned char* srcs = (unsigned char*)(ws + (size_t)6 * 1024 * 1024 + 512 * 128 * 4);
  float* out = (float*)d_out;

  gat1<<<512, 512, 0, stream>>>(x1, x2, e1, e2, Wl1, Wr1, bl1, br1, att1, bias1,
                                Wl2, Wr2, bl2, br2, xl2, xr2, meta, srcs);
  gat2<<<512, 512, 0, stream>>>(meta, srcs, xl2, xr2, att2, bias2, hfin);
  sinkout<<<256, 1024, 0, stream>>>(hfin, gamma, beta, out);
}

// Round 6
// 160.049 us; speedup vs baseline: 1.1345x; 1.0993x over previous
//
#include <hip/hip_runtime.h>

#define NB 64
#define NN 256
#define IND 7
#define HIDD 64
#define OUTD 32
#define EPG 8192
#define ETOT 524288
#define CAPQ 2600     // CSR capacity per 64-dst quarter (mean 2112, ~12 sigma)
#define SRCPAD 2624   // CAPQ rounded to 16

typedef _Float16 f16;
typedef f16 f16x2 __attribute__((ext_vector_type(2)));
typedef f16 f16x4 __attribute__((ext_vector_type(4)));
typedef f16 f16x8 __attribute__((ext_vector_type(8)));
typedef float f32x4 __attribute__((ext_vector_type(4)));

// ---------------- block reductions for 16-wave blocks ----------------
__device__ __forceinline__ float bsum16(float v, float* rb){
#pragma unroll
  for (int o = 32; o > 0; o >>= 1) v += __shfl_xor(v, o, 64);
  __syncthreads();
  if ((threadIdx.x & 63) == 0) rb[threadIdx.x >> 6] = v;
  __syncthreads();
  float s = 0.f;
#pragma unroll
  for (int i = 0; i < 16; i++) s += rb[i];
  return s;
}

__device__ __forceinline__ f16x2 lrelu2(f16x2 s){
  const f16x2 k = {(f16)0.2f, (f16)0.2f};
  return __builtin_elementwise_max(s, s * k);
}

// ---------------- GAT layer 1 + CSR build + lin2 (fused) -------------------
// grid 512, XCD-swizzled: gs = bid&127, quarter = bid>>7. 8 thr/dst.
// SPILL-KILL structure (R6): CSR passes run FIRST (edge regs die before the
// transforms), edges packed 2-per-u32 (ep2[9]), and score-phase fragments use
// f16x2[32] granules (R2's empirically spill-free layout). R5's f16x8
// fragments + long epk live range caused ~24.5MB scratch writes/dispatch.
// Transforms: wave-uniform dim slices -> W via scalar loads, 8-wide chunked
// accumulators, k-ascending fmaf chains -> bit-identical results.
// Epilogue: lin2 via MFMA on the block's 64 h rows -> xl2/xr2 (gat2 is then
// weight-free).
__global__ __launch_bounds__(512, 4) void gat1(
    const float* __restrict__ x1, const float* __restrict__ x2,
    const int* __restrict__ e1, const int* __restrict__ e2,
    const float* __restrict__ Wl, const float* __restrict__ Wr,
    const float* __restrict__ bl, const float* __restrict__ br,
    const float* __restrict__ att, const float* __restrict__ bias,
    const float* __restrict__ Wl2, const float* __restrict__ Wr2,
    const float* __restrict__ bl2, const float* __restrict__ br2,
    f16* __restrict__ xl2, f16* __restrict__ xr2,
    int* __restrict__ meta, unsigned char* __restrict__ srcs)
{
  __shared__ __align__(16) f16 xl_s[256 * 72];   // rows padded to 144B
  __shared__ __align__(16) f16 xr1_s[64 * 72];
  __shared__ __align__(16) f16 att_s[64];
  __shared__ float sc_s[CAPQ + 8];               // +8: chunked-read overrun pad
  __shared__ unsigned int src_su[SRCPAD / 4];
  __shared__ int deg_s[64], start_s[64], cnt_s[64];
  __shared__ unsigned char perm[64];
  unsigned char* src_s = (unsigned char*)src_su;

  const int bid = blockIdx.x;
  const int gs = bid & 127, lo = (bid >> 7) * 64;
  const int side = gs >> 6, g = gs & 63;
  const float* x = side ? x2 : x1;
  const int* eb = side ? e2 : e1;
  const int* es = eb + g * EPG;
  const int* ed = eb + ETOT + g * EPG;
  const int t = threadIdx.x;
  const int wv = t >> 6, lane64 = t & 63;

  if (t < 64){ deg_s[t] = 0; att_s[t] = (f16)att[t]; }

  // ---- single global edge read -> packed regs (2 edges per u32)
  unsigned int ep2[9];
  int nE = 0;
#pragma unroll
  for (int i = 0; i < 17; i++){
    int e = t + i * 512;
    if (e < EPG + 256){
      int sl, dl;
      if (e < EPG){ sl = es[e] & 255; dl = ed[e] & 255; }
      else { sl = dl = e - EPG; }
      unsigned int pk = (unsigned int)((dl << 8) | sl);
      if ((i & 1) == 0) ep2[i >> 1] = pk;
      else ep2[i >> 1] |= pk << 16;
      nE = i + 1;
    }
  }

  // ---- prefetch x rows for both transforms (issued early, consumed later)
  float xvl[IND], xvr[IND];
  {
    const int nodel = (wv & 3) * 64 + lane64;
    const float* pl = x + (g * 256 + nodel) * IND;
    const float* pr = x + (g * 256 + lo + lane64) * IND;
#pragma unroll
    for (int k = 0; k < IND; k++){ xvl[k] = pl[k]; xvr[k] = pr[k]; }
  }
  __syncthreads();   // deg zero + att_s visible

  // ---- CSR count pass (from packed regs)
#pragma unroll
  for (int i = 0; i < 17; i++) if (i < nE){
    unsigned int pk = (ep2[i >> 1] >> (16 * (i & 1))) & 0xFFFFu;
    int r = (int)(pk >> 8) - lo;
    if ((unsigned)r < 64u) atomicAdd(&deg_s[r], 1);
  }
  __syncthreads();
  // ---- scan + meta + degree-sort permutation
  if (t < 64){
    int v = deg_s[t], s = v;
#pragma unroll
    for (int off = 1; off < 64; off <<= 1){
      int u = __shfl_up(s, off, 64);
      if (t >= off) s += u;
    }
    start_s[t] = s - v;
    cnt_s[t] = s - v;
    meta[bid * 128 + t] = s - v;
    meta[bid * 128 + 64 + t] = v;
    int r = 0;
#pragma unroll 8
    for (int j = 0; j < 64; j++){
      int dj = deg_s[j];
      r += (dj < v) || (dj == v && j < t);
    }
    perm[r] = (unsigned char)t;
  }
  __syncthreads();
  // ---- fill pass (from packed regs; ep2 dies here)
#pragma unroll
  for (int i = 0; i < 17; i++) if (i < nE){
    unsigned int pk = (ep2[i >> 1] >> (16 * (i & 1))) & 0xFFFFu;
    int r = (int)(pk >> 8) - lo;
    if ((unsigned)r < 64u){
      int p = atomicAdd(&cnt_s[r], 1);
      if (p < CAPQ) src_s[p] = (unsigned char)(pk & 255u);
    }
  }
  __syncthreads();
  // ---- dump CSR srcs to global for gat2 (coalesced u32)
  {
    int ttl = start_s[63] + deg_s[63];
    if (ttl > CAPQ) ttl = CAPQ;
    unsigned int* gsrc = (unsigned int*)(srcs + (size_t)bid * SRCPAD);
    int nw = (ttl + 3) >> 2;
    for (int i = t; i < nw; i += 512) gsrc[i] = src_su[i];
  }

  // ---- xl = x@Wl + bl: wave wv -> nodes (wv&3)*64+lane, dims (wv>>2)*32..+32
  // chunked 8-wide accumulators; W/b wave-uniform -> scalar loads.
  {
    const int ng = wv & 3, dh = wv >> 2;
    const int node = ng * 64 + lane64;
#pragma unroll
    for (int ch = 0; ch < 4; ch++){
      const int d0 = dh * 32 + ch * 8;
      float a[8];
#pragma unroll
      for (int d = 0; d < 8; d++) a[d] = bl[d0 + d];
#pragma unroll
      for (int k = 0; k < IND; k++){
        float xk = xvl[k];
#pragma unroll
        for (int d = 0; d < 8; d++)
          a[d] = fmaf(xk, Wl[k * HIDD + d0 + d], a[d]);
      }
      f16x8 o;
#pragma unroll
      for (int j = 0; j < 8; j++) o[j] = (f16)a[j];
      *(f16x8*)&xl_s[node * 72 + d0] = o;
    }
  }
  // ---- xr = x@Wr + br for the 64 dsts: wave wv -> dims wv*8..+8, node=lane
  {
    const int d0 = wv * 8;
    float a[8];
#pragma unroll
    for (int d = 0; d < 8; d++) a[d] = br[d0 + d];
#pragma unroll
    for (int k = 0; k < IND; k++){
      float xk = xvr[k];
#pragma unroll
      for (int d = 0; d < 8; d++)
        a[d] = fmaf(xk, Wr[k * HIDD + d0 + d], a[d]);
    }
    f16x8 o;
#pragma unroll
    for (int j = 0; j < 8; j++) o[j] = (f16)a[j];
    *(f16x8*)&xr1_s[lane64 * 72 + d0] = o;
  }
  __syncthreads();   // xl_s + xr1_s visible

  // ---- 8 threads/dst (degree-sorted): xr + att fragments as f16x2 granules
  const int pairi = perm[t >> 3], sub = t & 7, ln = lo + pairi;
  f16x2 xrh[32], atth[32];
  {
    const f16x8* xrp = (const f16x8*)&xr1_s[pairi * 72];
    const f16x8* atp = (const f16x8*)att_s;
#pragma unroll
    for (int q = 0; q < 8; q++){
      f16x8 v = xrp[q], a_ = atp[q];
#pragma unroll
      for (int u = 0; u < 4; u++){
        xrh[q * 4 + u][0] = v[2 * u];
        xrh[q * 4 + u][1] = v[2 * u + 1];
        atth[q * 4 + u][0] = a_[2 * u];
        atth[q * 4 + u][1] = a_[2 * u + 1];
      }
    }
  }

  // ---- scores + exp fused: edge-split (each thread every-8th edge, 64 dims)
  const int s0 = start_s[pairi];
  int sE = s0 + deg_s[pairi];
  if (sE > CAPQ) sE = CAPQ;
  float ssum = 0.f;
  for (int idx = s0 + sub; idx < sE; idx += 8){
    int sl = src_s[idx];
    const f16x8* rp = (const f16x8*)&xl_s[(unsigned)sl * 72];
    float accs[4] = {0.f, 0.f, 0.f, 0.f};
#pragma unroll
    for (int blk = 0; blk < 8; blk++){
      f16x8 rv = rp[blk];
#pragma unroll
      for (int u = 0; u < 4; u++){
        f16x2 v = {rv[2 * u], rv[2 * u + 1]};
        v = v + xrh[blk * 4 + u];
        accs[u] = __builtin_amdgcn_fdot2(lrelu2(v), atth[blk * 4 + u], accs[u], false);
      }
    }
    float w = __expf((accs[0] + accs[1]) + (accs[2] + accs[3]));
    sc_s[idx] = w;
    ssum += w;
  }
  ssum += __shfl_xor(ssum, 1, 64);
  ssum += __shfl_xor(ssum, 2, 64);
  ssum += __shfl_xor(ssum, 4, 64);
  float inv = 1.f / ssum;
  // ---- aggregate alpha * xl[src], dim-split 8 ways, 4-deep pipelined.
  float acc[8];
#pragma unroll
  for (int c = 0; c < 8; c++) acc[c] = 0.f;
  for (int base = s0; base < sE; base += 4){
    f16x8 rows[4]; float wv_[4];
#pragma unroll
    for (int k = 0; k < 4; k++){
      int sl = src_s[base + k];
      rows[k] = *(const f16x8*)&xl_s[(unsigned)sl * 72 + sub * 8];
      wv_[k] = sc_s[base + k];
    }
#pragma unroll
    for (int k = 0; k < 4; k++){
      float w = (base + k < sE) ? wv_[k] : 0.f;
#pragma unroll
      for (int c = 0; c < 8; c++) acc[c] = fmaf(w, (float)rows[k][c], acc[c]);
    }
  }
  f16x8 o;
#pragma unroll
  for (int c = 0; c < 8; c++)
    o[c] = (f16)fmaxf(acc[c] * inv + bias[sub * 8 + c], 0.f);

  // ---- lin2 epilogue: h rows -> xl_s rows 0..63 (xl_s dead), then MFMA
  __syncthreads();                        // all xl_s readers done
  *(f16x8*)&xl_s[pairi * 72 + sub * 8] = o;
  __syncthreads();
  if (wv < 4){
    const int m = lane64 & 15, quad = lane64 >> 4;
    const int row = wv * 16 + m;
    f16x8 a0 = *(const f16x8*)&xl_s[row * 72 + quad * 8];
    f16x8 a1 = *(const f16x8*)&xl_s[row * 72 + 32 + quad * 8];
#pragma unroll
    for (int mat = 0; mat < 2; mat++){
      const float* W = mat ? Wr2 : Wl2;
      const float* bb = mat ? br2 : bl2;
      f16* dst = mat ? xr2 : xl2;
#pragma unroll
      for (int H = 0; H < 2; H++){
        const int n = H * 16 + m;
        f16x8 b0, b1;
#pragma unroll
        for (int j = 0; j < 8; j++){
          b0[j] = (f16)W[(quad * 8 + j) * 32 + n];
          b1[j] = (f16)W[(32 + quad * 8 + j) * 32 + n];
        }
        const float bv = bb[n];
        f32x4 accm = {0.f, 0.f, 0.f, 0.f};
        accm = __builtin_amdgcn_mfma_f32_16x16x32_f16(a0, b0, accm, 0, 0, 0);
        accm = __builtin_amdgcn_mfma_f32_16x16x32_f16(a1, b1, accm, 0, 0, 0);
#pragma unroll
        for (int r = 0; r < 4; r++)
          dst[(size_t)(gs * 256 + lo + wv * 16 + quad * 4 + r) * 32 + n]
              = (f16)(accm[r] + bv);
      }
    }
  }
}

// ---------------- GAT layer 2 (no weights: consumes xl2/xr2) ---------------
// Same grid/swizzle as gat1; CSR slot = blockIdx.x (matches gat1's store).
__global__ __launch_bounds__(512, 4) void gat2(
    const int* __restrict__ meta, const unsigned char* __restrict__ srcs,
    const f16* __restrict__ xl2, const f16* __restrict__ xr2,
    const float* __restrict__ att, const float* __restrict__ bias,
    f16* __restrict__ hout)
{
  __shared__ __align__(16) f16 xl_s[256 * 40];   // rows padded to 80B
  __shared__ __align__(16) f16 xr_s[64 * 40];
  __shared__ float sc_s[CAPQ + 8];               // +8: chunked-read overrun pad
  __shared__ unsigned int src_su[SRCPAD / 4];
  __shared__ int start_s[64], deg_s[64];
  __shared__ unsigned char perm[64];
  unsigned char* src_s = (unsigned char*)src_su;

  const int bid = blockIdx.x;                    // same mapping as gat1
  const int gs = bid & 127, lo = (bid >> 7) * 64;
  const int t = threadIdx.x;

  // ---- CSR load (global -> LDS)
  if (t < 64){
    start_s[t] = meta[bid * 128 + t];
    deg_s[t] = meta[bid * 128 + 64 + t];
  }
  {
    int ttl = meta[bid * 128 + 63] + meta[bid * 128 + 64 + 63];
    if (ttl > CAPQ) ttl = CAPQ;
    const unsigned int* gsrc = (const unsigned int*)(srcs + (size_t)bid * SRCPAD);
    int nw = (ttl + 3) >> 2;
    for (int i = t; i < nw; i += 512) src_su[i] = gsrc[i];
  }

  // ---- stage xl2 (all 256 srcs) and xr2 (own 64 dsts): coalesced copies
  {
    const int row = t >> 1, half = t & 1;
    const f16* s_ = xl2 + (size_t)(gs * 256 + row) * 32 + half * 16;
    *(f16x8*)&xl_s[row * 40 + half * 16] = *(const f16x8*)s_;
    *(f16x8*)&xl_s[row * 40 + half * 16 + 8] = *(const f16x8*)(s_ + 8);
    if (t < 128){
      const f16* s2_ = xr2 + (size_t)(gs * 256 + lo + row) * 32 + half * 16;
      *(f16x8*)&xr_s[row * 40 + half * 16] = *(const f16x8*)s2_;
      *(f16x8*)&xr_s[row * 40 + half * 16 + 8] = *(const f16x8*)(s2_ + 8);
    }
  }
  __syncthreads();
  // ---- degree-sort permutation
  if (t < 64){
    int v = deg_s[t], r = 0;
#pragma unroll 8
    for (int j = 0; j < 64; j++){
      int dj = deg_s[j];
      r += (dj < v) || (dj == v && j < t);
    }
    perm[r] = (unsigned char)t;
  }
  __syncthreads();

  // ---- 8 threads/dst (sorted): full 32-dim xr + att in regs
  const int pairi = perm[t >> 3], sub = t & 7, ln = lo + pairi;
  f16x2 xrh[16], atth[16];
  {
    const f16x8* xrp = (const f16x8*)&xr_s[pairi * 40];
#pragma unroll
    for (int q = 0; q < 4; q++){
      f16x8 v = xrp[q];
#pragma unroll
      for (int u = 0; u < 4; u++){
        xrh[q * 4 + u][0] = v[2 * u];
        xrh[q * 4 + u][1] = v[2 * u + 1];
      }
    }
#pragma unroll
    for (int i = 0; i < 16; i++){
      atth[i][0] = (f16)att[2 * i];
      atth[i][1] = (f16)att[2 * i + 1];
    }
  }

  // ---- scores + exp fused: edge-split
  const int s0 = start_s[pairi];
  int sE = s0 + deg_s[pairi];
  if (sE > CAPQ) sE = CAPQ;
  float ssum = 0.f;
  for (int idx = s0 + sub; idx < sE; idx += 8){
    int sl = src_s[idx];
    const f16x8* rp = (const f16x8*)&xl_s[(unsigned)sl * 40];
    float accs[4] = {0.f, 0.f, 0.f, 0.f};
#pragma unroll
    for (int blk = 0; blk < 4; blk++){
      f16x8 rv = rp[blk];
#pragma unroll
      for (int u = 0; u < 4; u++){
        f16x2 v = {rv[2 * u], rv[2 * u + 1]};
        v = v + xrh[blk * 4 + u];
        accs[u] = __builtin_amdgcn_fdot2(lrelu2(v), atth[blk * 4 + u], accs[u], false);
      }
    }
    float w = __expf((accs[0] + accs[1]) + (accs[2] + accs[3]));
    sc_s[idx] = w;
    ssum += w;
  }
  ssum += __shfl_xor(ssum, 1, 64);
  ssum += __shfl_xor(ssum, 2, 64);
  ssum += __shfl_xor(ssum, 4, 64);
  float inv = 1.f / ssum;

  // ---- aggregate, dim-split 4 ways per thread-octet, 8-deep pipelined
  float acc[4];
#pragma unroll
  for (int c = 0; c < 4; c++) acc[c] = 0.f;
  for (int base = s0; base < sE; base += 8){
    f16x4 rows[8]; float wv[8];
#pragma unroll
    for (int k = 0; k < 8; k++){
      int sl = src_s[base + k];
      rows[k] = *(const f16x4*)&xl_s[(unsigned)sl * 40 + sub * 4];
      wv[k] = sc_s[base + k];
    }
#pragma unroll
    for (int k = 0; k < 8; k++){
      float w = (base + k < sE) ? wv[k] : 0.f;
#pragma unroll
      for (int c = 0; c < 4; c++) acc[c] = fmaf(w, (float)rows[k][c], acc[c]);
    }
  }
  f16x4 o;
#pragma unroll
  for (int c = 0; c < 4; c++)
    o[c] = (f16)(acc[c] * inv + bias[sub * 4 + c]);
  *(f16x4*)(hout + (size_t)(gs * 256 + ln) * 32 + sub * 4) = o;
}

// ---------------- sinkout: fused sim + stats + histogram Sinkhorn + output --
// grid 256 XCD-swizzled (b = bid&63, q = bid>>6), 1024 thr (16 waves).
__global__ __launch_bounds__(1024) void sinkout(
    const f16* __restrict__ H,
    const float* __restrict__ gamma, const float* __restrict__ beta,
    float* __restrict__ out)
{
  __shared__ float rb[16];
  __shared__ __align__(16) float rb4s[64];   // 16 waves x (sum,sumsq,min,max)
  __shared__ unsigned int hist[8192];
  const int b = blockIdx.x & 63, q = blockIdx.x >> 6, t = threadIdx.x;
  const int w = t >> 6, lane = t & 63;
  const int m = lane & 15, quad = lane >> 4;

  const f16* h1 = H + (size_t)b * 256 * 32;
  const f16* h2 = H + (size_t)(64 + b) * 256 * 32;

  f16x8 av = *(const f16x8*)(h1 + (size_t)(w * 16 + m) * 32 + quad * 8);
  f32x4 c[16];
#pragma unroll
  for (int j = 0; j < 16; j++){
    f16x8 bv = *(const f16x8*)(h2 + (size_t)(j * 16 + m) * 32 + quad * 8);
    f32x4 z = {0.f, 0.f, 0.f, 0.f};
    c[j] = __builtin_amdgcn_mfma_f32_16x16x32_f16(av, bv, z, 0, 0, 0);
  }

  // ---- stats over reg-resident sim: packed single-barrier reduction
  float sm = 0.f, s2 = 0.f, mn = 3.0e38f, mx = -3.0e38f;
#pragma unroll
  for (int j = 0; j < 16; j++)
#pragma unroll
    for (int r = 0; r < 4; r++){
      float s = c[j][r];
      sm += s; s2 = fmaf(s, s, s2);
      mn = fminf(mn, s); mx = fmaxf(mx, s);
    }
#pragma unroll
  for (int o = 32; o > 0; o >>= 1){
    sm += __shfl_xor(sm, o, 64);
    s2 += __shfl_xor(s2, o, 64);
    mn = fminf(mn, __shfl_xor(mn, o, 64));
    mx = fmaxf(mx, __shfl_xor(mx, o, 64));
  }
  if (lane == 0){
    rb4s[w * 4 + 0] = sm; rb4s[w * 4 + 1] = s2;
    rb4s[w * 4 + 2] = mn; rb4s[w * 4 + 3] = mx;
  }
  // hist zero-init shares the same barrier
  for (int i = t; i < 8192; i += 1024) hist[i] = 0u;
  __syncthreads();
  sm = 0.f; s2 = 0.f; mn = 3.0e38f; mx = -3.0e38f;
#pragma unroll
  for (int i = 0; i < 16; i++){
    sm += rb4s[i * 4 + 0];
    s2 += rb4s[i * 4 + 1];
    mn = fminf(mn, rb4s[i * 4 + 2]);
    mx = fmaxf(mx, rb4s[i * 4 + 3]);
  }

  const float mu = sm * (1.f / 65536.f);
  const float var = s2 * (1.f / 65536.f) - mu * mu;
  const float a = gamma[0] * rsqrtf(var + 1e-5f);
  const float cc = beta[0] - a * mu;
  float mnn = a * mn + cc, mxn = a * mx + cc;
  if (a < 0.f){ float tmp = mnn; mnn = mxn; mxn = tmp; }
  const float al = 2.f * a;
  const float be = 2.f * cc - mnn - mxn;
  const float R = fmaxf(mxn - mnn, 1e-12f);       // z in [-R, R]
  const float binscale = 4096.f / R;

  // ---- histogram from f32 sim (hist already zeroed before the barrier)
#pragma unroll
  for (int j = 0; j < 16; j++)
#pragma unroll
    for (int r = 0; r < 4; r++){
      float z = fmaf(al, c[j][r], be);
      int bi = (int)fmaf(z, binscale, 4096.f);
      bi = min(max(bi, 0), 8191);
      atomicAdd(&hist[bi], 1u);
    }
  __syncthreads();

  // ---- 5 S_p reductions over bins (8 bins/thread)
  const float wbin = R * (1.f / 4096.f);
  float ebs[8], cnts[8];
#pragma unroll
  for (int j = 0; j < 8; j++){
    float zc = fmaf((float)(t * 8 + j) + 0.5f, wbin, -R);
    ebs[j] = __expf(-zc);
    cnts[j] = (float)hist[t * 8 + j];
  }

  float D = 0.f, S = 256.f, eD = 1.f;
  for (int p = 0; p < 5; p++){
    float loc = 0.f;
#pragma unroll
    for (int j = 0; j < 8; j++)
      loc += cnts[j] / (1.f + ebs[j] * eD);
    S = bsum16(loc, rb);
    if (p < 4){
      D += -5.5412635f /* log(256/65280) */ + __logf(65536.f - S) - __logf(S);
      eD = __expf(-D);
    }
  }

  // ---- write my 64-row quarter: waves 4q..4q+3 own rows [64q, 64q+64)
  const float beD = be + D;
  const float scale = 256.f / S;
  if ((w >> 2) == q){
    float* ob = out + (size_t)b * 65536;
#pragma unroll
    for (int j = 0; j < 16; j++){
#pragma unroll
      for (int r = 0; r < 4; r++){
        float zz = fmaf(al, c[j][r], beD);
        float v = fminf(scale / (1.f + __expf(-zz)), 1.f);
        ob[(w * 16 + quad * 4 + r) * 256 + j * 16 + m] = v;
      }
    }
  }
}

extern "C" void kernel_launch(void* const* d_in, const int* in_sizes, int n_in,
                              void* d_out, int out_size, void* d_ws, size_t ws_size,
                              hipStream_t stream)
{
  const float* x1   = (const float*)d_in[0];
  const float* x2   = (const float*)d_in[1];
  const int*   e1   = (const int*)d_in[2];
  const int*   e2   = (const int*)d_in[3];
  const float* Wl1  = (const float*)d_in[4];
  const float* Wr1  = (const float*)d_in[5];
  const float* bl1  = (const float*)d_in[6];
  const float* br1  = (const float*)d_in[7];
  const float* att1 = (const float*)d_in[8];
  const float* bias1= (const float*)d_in[9];
  const float* Wl2  = (const float*)d_in[10];
  const float* Wr2  = (const float*)d_in[11];
  const float* bl2  = (const float*)d_in[12];
  const float* br2  = (const float*)d_in[13];
  const float* att2 = (const float*)d_in[14];
  const float* bias2= (const float*)d_in[15];
  const float* gamma= (const float*)d_in[16];
  const float* beta = (const float*)d_in[17];

  // ws (~7.9 MB): hfin [0,2M); xl2 [2M,4M); xr2 [4M,6M); meta [6M,+256K);
  // srcs [+256K,+1.6M).
  char* ws = (char*)d_ws;
  f16* hfin = (f16*)ws;
  f16* xl2 = (f16*)(ws + (size_t)2 * 1024 * 1024);
  f16* xr2 = (f16*)(ws + (size_t)4 * 1024 * 1024);
  int* meta = (int*)(ws + (size_t)6 * 1024 * 1024);
  unsigned char* srcs = (unsigned char*)(ws + (size_t)6 * 1024 * 1024 + 512 * 128 * 4);
  float* out = (float*)d_out;

  gat1<<<512, 512, 0, stream>>>(x1, x2, e1, e2, Wl1, Wr1, bl1, br1, att1, bias1,
                                Wl2, Wr2, bl2, br2, xl2, xr2, meta, srcs);
  gat2<<<512, 512, 0, stream>>>(meta, srcs, xl2, xr2, att2, bias2, hfin);
  sinkout<<<256, 1024, 0, stream>>>(hfin, gamma, beta, out);
}